// Round 17
// baseline (381.513 us; speedup 1.0000x reference)
//
#include <hip/hip_runtime.h>
#include <hip/hip_bf16.h>
#include <math.h>

typedef __attribute__((ext_vector_type(8))) short short8;
typedef __attribute__((ext_vector_type(4))) float f32x4;
typedef __attribute__((ext_vector_type(4))) unsigned int uint4v;

struct __align__(8) U2 { unsigned int x, y; };

#define DEVI static __device__ __forceinline__

DEVI unsigned pk1(float f){ unsigned u = __float_as_uint(f); return (u + 0x7fffu + ((u>>16)&1u)) >> 16; }
DEVI unsigned pk2(float a, float b){
  __hip_bfloat162 h = __float22bfloat162_rn(float2{a, b});   // v_cvt_pk_bf16_f32 (RNE)
  union { __hip_bfloat162 h; unsigned u; } c; c.h = h; return c.u;
}
DEVI float bfu(unsigned hs){ return __uint_as_float((hs & 0xffffu) << 16); }

DEVI short8 lds8(const unsigned short* p){
  union { short8 v; U2 u[2]; } f;
  f.u[0] = *(const U2*)p;
  f.u[1] = *(const U2*)(p + 4);
  return f.v;
}
DEVI short8 mk8(unsigned a, unsigned b, unsigned c, unsigned d){
  union { short8 v; unsigned u[4]; } f; f.u[0]=a; f.u[1]=b; f.u[2]=c; f.u[3]=d; return f.v;
}
DEVI short8 zero8(){ return mk8(0,0,0,0); }
DEVI short8 gfrag(const unsigned short* p){ union { short8 v; uint4v u; } f; f.u = *(const uint4v*)p; return f.v; }
DEVI f32x4 MFMA(short8 a, short8 b, f32x4 c){ return __builtin_amdgcn_mfma_f32_16x16x32_bf16(a, b, c, 0, 0, 0); }
DEVI void st2(unsigned short* p, unsigned lo, unsigned hi){ U2 t; t.x=lo; t.y=hi; *(U2*)p = t; }

DEVI float fastrcp(float x){ float r; asm("v_rcp_f32 %0, %1" : "=v"(r) : "v"(x)); return r; }
// tanh-form GELU: v * sigmoid(1.5957691*(v + 0.044715 v^3)); max err ~3e-4
DEVI float gelu_f(float v){
  float z2 = fmaf(v*v*v, -0.07135481627f, -1.5957691216f*v);
  return v * fastrcp(1.f + __expf(z2));
}

// 1/sqrt(24) * log2(e): QK^T scores come out in base-2 units -> exp2f (bare v_exp)
#define QSCALE 0.29448851924592855f

// ---------------------------------------------------------------------------
// prep: weights -> bf16 MFMA fragment arrays in ws. (r16 verbatim)
// Fragment map: m/n = 16*mt + (lane&15), k = 32*kb + 8*(lane>>4) + j.
// Offsets (ushort): AQT=0, AKT=9216, AVT=18432, AOT=27648, A1T=36864, A2T=73728
// ---------------------------------------------------------------------------
__global__ __launch_bounds__(256) void prep_kernel(
    const float* __restrict__ wq, const float* __restrict__ wk,
    const float* __restrict__ wv, const float* __restrict__ wo,
    const float* __restrict__ w1, const float* __restrict__ w2,
    unsigned short* __restrict__ wfr)
{
  int i = blockIdx.x * 256 + threadIdx.x;
  if (i >= 110592) return;
  int j = i & 7, lane = (i >> 3) & 63, fr = i >> 9;
  int ln = lane & 15, lg = lane >> 4;
  float v;
  if (fr < 18)      { int s = fr;       int mt = s/3,  kb = s%3;  v = wq[(32*kb + 8*lg + j)*96  + 16*mt + ln] * QSCALE; }
  else if (fr < 36) { int s = fr - 18;  int mt = s/3,  kb = s%3;  v = wk[(32*kb + 8*lg + j)*96  + 16*mt + ln]; }
  else if (fr < 54) { int s = fr - 36;  int mt = s/3,  kb = s%3;  v = wv[(32*kb + 8*lg + j)*96  + 16*mt + ln]; }
  else if (fr < 72) { int s = fr - 54;  int mt = s/3,  kb = s%3;  v = wo[(32*kb + 8*lg + j)*96  + 16*mt + ln]; }
  else if (fr < 144){ int s = fr - 72;  int mt = s/3,  kb = s%3;  v = w1[(32*kb + 8*lg + j)*384 + 16*mt + ln]; }
  else              { int s = fr - 144; int mt = s/12, kb = s%12; v = w2[(32*kb + 8*lg + j)*96  + 16*mt + ln]; }
  wfr[i] = (unsigned short)pk1(v);
}

// ---------------------------------------------------------------------------
// Attention kernel: one 7x7 window per block, 4 waves, ONE barrier.
// NEW vs r16: x loaded in fragment-channel order {32kb+8lg+j}; LN done in
// registers (2 shfl, full-96 stats since lanes with equal ln share token);
// bx built in registers -> XN buffer and barrier A deleted. Residual held in
// a second register set xr[] (residual channel layout). Rest = r16 ph2-ph4.
// LDS 48,448 B -> 3 blocks/CU.
// ---------------------------------------------------------------------------
__global__ __launch_bounds__(256, 3) void attn_kernel(
    const float* __restrict__ x, const float* __restrict__ emap,
    const float* __restrict__ beta_p,
    const float* __restrict__ bq, const float* __restrict__ bk,
    const float* __restrict__ bv, const float* __restrict__ bo,
    const float* __restrict__ g1, const float* __restrict__ b1,
    const unsigned short* __restrict__ wfr,
    unsigned short* __restrict__ xres)
{
  __shared__ __align__(16) char smem[48448];
  unsigned short* VT = (unsigned short*)(smem);            // [104][68] v^T (14,144 B)
  unsigned short* QS = (unsigned short*)(smem + 14144);    // [64][100] q -> o_s (wave-local)
  unsigned short* KS = (unsigned short*)(smem + 26944);    // [64][100] k
  unsigned short* PB = (unsigned short*)(smem + 39744);    // [4][16][68] P roundtrip

  const int tid = threadIdx.x, lane = tid & 63;
  const int w = tid >> 6, lg = lane >> 4, ln = lane & 15;

  int bid = blockIdx.x;
  int bw  = ((bid & 7) << 10) | (bid >> 3);   // XCD swizzle: one image per XCD
  const int b  = bw >> 10;
  const int rr = bw & 1023;
  const int h0w = (rr >> 5) * 7;
  const int w0w = (rr & 31) * 7;
  const int t = 16*w + ln;
  const bool tv = (t < 49);

  // ---- ph1: dual x loads; LN in registers; bx fragments in registers ----
  float xr[24];        // residual layout: channels 16*mt + 4*lg + r (held to ph4)
  short8 bx0, bx1, bx2;
  float ewv = 0.f;
  size_t pixloc = 0;
  {
    float xf[24];      // fragment layout: channels 32*kb + 8*lg + j
    if (tv){
      pixloc = (size_t)(h0w + t/7)*224 + w0w + t%7;
      const float* xpf = x + (size_t)(b*96 + 8*lg)*50176 + pixloc;
#pragma unroll
      for (int kb = 0; kb < 3; ++kb)
#pragma unroll
        for (int j = 0; j < 8; ++j) xf[kb*8+j] = xpf[(size_t)(32*kb + j)*50176];
      const float* xpr = x + (size_t)(b*96 + 4*lg)*50176 + pixloc;
#pragma unroll
      for (int mt = 0; mt < 6; ++mt)
#pragma unroll
        for (int r = 0; r < 4; ++r) xr[mt*4+r] = xpr[(size_t)(16*mt + r)*50176];
      ewv = emap[(size_t)b*50176 + pixloc];
    } else {
#pragma unroll
      for (int i = 0; i < 24; ++i){ xf[i] = 0.f; xr[i] = 0.f; }
    }
    float s = 0.f, s2 = 0.f;
#pragma unroll
    for (int i = 0; i < 24; ++i){ s += xf[i]; s2 += xf[i]*xf[i]; }
    s  += __shfl_xor(s, 16);  s  += __shfl_xor(s, 32);
    s2 += __shfl_xor(s2, 16); s2 += __shfl_xor(s2, 32);
    float m = s * (1.f/96.f);
    float var = s2 * (1.f/96.f) - m*m;
    float rstd = rsqrtf(var + 1e-5f);
#pragma unroll
    for (int kb = 0; kb < 3; ++kb){
      int c = 32*kb + 8*lg;
      unsigned u0 = pk2((xf[kb*8+0]-m)*rstd*g1[c+0]+b1[c+0], (xf[kb*8+1]-m)*rstd*g1[c+1]+b1[c+1]);
      unsigned u1 = pk2((xf[kb*8+2]-m)*rstd*g1[c+2]+b1[c+2], (xf[kb*8+3]-m)*rstd*g1[c+3]+b1[c+3]);
      unsigned u2 = pk2((xf[kb*8+4]-m)*rstd*g1[c+4]+b1[c+4], (xf[kb*8+5]-m)*rstd*g1[c+5]+b1[c+5]);
      unsigned u3 = pk2((xf[kb*8+6]-m)*rstd*g1[c+6]+b1[c+6], (xf[kb*8+7]-m)*rstd*g1[c+7]+b1[c+7]);
      short8 bxk = mk8(u0, u1, u2, u3);
      if (kb == 0) bx0 = bxk; else if (kb == 1) bx1 = bxk; else bx2 = bxk;
    }
  }

  // ---- ph2: Q,K -> QS,KS (own rows); V^T -> VT (own token col t) ----
  {
#pragma unroll
    for (int mt = 0; mt < 6; ++mt){
      int d0 = 16*mt + 4*lg;
      f32x4 aq, ak;
#pragma unroll
      for (int r = 0; r < 4; ++r){ aq[r] = bq[d0+r]*QSCALE; ak[r] = bk[d0+r]; }
      aq = MFMA(gfrag(wfr +        (mt*3+0)*512 + lane*8), bx0, aq);
      aq = MFMA(gfrag(wfr +        (mt*3+1)*512 + lane*8), bx1, aq);
      aq = MFMA(gfrag(wfr +        (mt*3+2)*512 + lane*8), bx2, aq);
      ak = MFMA(gfrag(wfr + 9216 + (mt*3+0)*512 + lane*8), bx0, ak);
      ak = MFMA(gfrag(wfr + 9216 + (mt*3+1)*512 + lane*8), bx1, ak);
      ak = MFMA(gfrag(wfr + 9216 + (mt*3+2)*512 + lane*8), bx2, ak);
      st2(QS + t*100 + d0, pk2(aq[0],aq[1]), pk2(aq[2],aq[3]));
      st2(KS + t*100 + d0, pk2(ak[0],ak[1]), pk2(ak[2],ak[3]));
    }
#pragma unroll
    for (int mt = 0; mt < 6; ++mt){
      int d0 = 16*mt + 4*lg;
      f32x4 av;
#pragma unroll
      for (int r = 0; r < 4; ++r) av[r] = bv[d0+r];
      av = MFMA(gfrag(wfr + 18432 + (mt*3+0)*512 + lane*8), bx0, av);
      av = MFMA(gfrag(wfr + 18432 + (mt*3+1)*512 + lane*8), bx1, av);
      av = MFMA(gfrag(wfr + 18432 + (mt*3+2)*512 + lane*8), bx2, av);
#pragma unroll
      for (int r = 0; r < 4; ++r) VT[(d0+r)*68 + t] = (unsigned short)pk1(av[r]);
    }
  }
  __syncthreads();   // the ONLY barrier: QS/KS/VT published

  // ---- ph3: attention, paired heads; P via wave-local LDS; shfl denom ----
  const float beta = beta_p[0];
  const float gq   = __expf(-beta * ewv);
  const float gfac = gq / (gq + 1e-9f);
  f32x4 mz;  mz[0]=0.f; mz[1]=0.f; mz[2]=0.f; mz[3]=0.f;
  f32x4 m3;  // pad-key mask (base-2 logits): keys > 48 get -50
#pragma unroll
  for (int r = 0; r < 4; ++r) m3[r] = (4*lg + r >= 1) ? -50.f : 0.f;
  unsigned short* PBw = PB + (w*16 + ln)*68;

#pragma unroll
  for (int hp = 0; hp < 2; ++hp){
    const int h0 = 2*hp, h1 = 2*hp + 1;

    short8 bqf0 = (lg < 3) ? lds8(QS + t*100 + 24*h0 + 8*lg) : zero8();
    short8 bqf1 = (lg < 3) ? lds8(QS + t*100 + 24*h1 + 8*lg) : zero8();
    f32x4 sv0[4], sv1[4];
#pragma unroll
    for (int mt = 0; mt < 4; ++mt){
      short8 af0 = (lg < 3) ? lds8(KS + (16*mt+ln)*100 + 24*h0 + 8*lg) : zero8();
      short8 af1 = (lg < 3) ? lds8(KS + (16*mt+ln)*100 + 24*h1 + 8*lg) : zero8();
      f32x4 ci = (mt == 3) ? m3 : mz;
      sv0[mt] = MFMA(af0, bqf0, ci);
      sv1[mt] = MFMA(af1, bqf1, ci);
    }

    // exp2 (scores already base-2); no max-sub (scores provably small)
    float vv0[16], vv1[16];
    float ss0 = 0.f, ss1 = 0.f;
#pragma unroll
    for (int i = 0; i < 16; ++i){
      float e0 = exp2f(sv0[i>>2][i&3]); vv0[i] = e0; ss0 += e0;
      float e1 = exp2f(sv1[i>>2][i&3]); vv1[i] = e1; ss1 += e1;
    }
    ss0 += __shfl_xor(ss0, 16);  ss1 += __shfl_xor(ss1, 16);
    ss0 += __shfl_xor(ss0, 32);  ss1 += __shfl_xor(ss1, 32);
    float inv0 = gfac * fastrcp(ss0);
    float inv1 = gfac * fastrcp(ss1);

    // P roundtrip via wave-local LDS (in-order DS pipe, no barrier)
#pragma unroll
    for (int mt = 0; mt < 4; ++mt)
      st2(PBw + 16*mt + 4*lg,
          pk2(vv0[4*mt+0], vv0[4*mt+1]), pk2(vv0[4*mt+2], vv0[4*mt+3]));
    short8 pf00 = lds8(PBw + 0  + 8*lg);
    short8 pf01 = lds8(PBw + 32 + 8*lg);
#pragma unroll
    for (int mt = 0; mt < 4; ++mt)
      st2(PBw + 16*mt + 4*lg,
          pk2(vv1[4*mt+0], vv1[4*mt+1]), pk2(vv1[4*mt+2], vv1[4*mt+3]));
    short8 pf10 = lds8(PBw + 0  + 8*lg);
    short8 pf11 = lds8(PBw + 32 + 8*lg);

#pragma unroll
    for (int mt = 0; mt < 2; ++mt){
      f32x4 pv0; pv0[0]=0.f; pv0[1]=0.f; pv0[2]=0.f; pv0[3]=0.f;
      f32x4 pv1; pv1[0]=0.f; pv1[1]=0.f; pv1[2]=0.f; pv1[3]=0.f;
      pv0 = MFMA(lds8(VT + (24*h0+16*mt+ln)*68 + 0  + 8*lg), pf00, pv0);
      pv1 = MFMA(lds8(VT + (24*h1+16*mt+ln)*68 + 0  + 8*lg), pf10, pv1);
      pv0 = MFMA(lds8(VT + (24*h0+16*mt+ln)*68 + 32 + 8*lg), pf01, pv0);
      pv1 = MFMA(lds8(VT + (24*h1+16*mt+ln)*68 + 32 + 8*lg), pf11, pv1);
      if (!(mt == 1 && lg >= 2)){
        st2(QS + t*100 + 24*h0 + 16*mt + 4*lg,
            pk2(pv0[0]*inv0, pv0[1]*inv0), pk2(pv0[2]*inv0, pv0[3]*inv0));
        st2(QS + t*100 + 24*h1 + 16*mt + 4*lg,
            pk2(pv1[0]*inv1, pv1[1]*inv1), pk2(pv1[2]*inv1, pv1[3]*inv1));
      }
    }
  }

  // ---- ph4: proj + residual (xr regs) -> xres bf16 [pix][96] ----
  {
    f32x4 po[6];
#pragma unroll
    for (int mt = 0; mt < 6; ++mt){
      int c0 = 16*mt + 4*lg;
#pragma unroll
      for (int r = 0; r < 4; ++r) po[mt][r] = bo[c0+r];
    }
#pragma unroll
    for (int kb = 0; kb < 3; ++kb){
      short8 bf_ = lds8(QS + t*100 + 32*kb + 8*lg);   // own row (o_s), all heads done
#pragma unroll
      for (int mt = 0; mt < 6; ++mt)
        po[mt] = MFMA(gfrag(wfr + 27648 + (mt*3+kb)*512 + lane*8), bf_, po[mt]);
    }
    if (tv){
      unsigned short* xo = xres + ((size_t)b*50176 + pixloc)*96;
#pragma unroll
      for (int mt = 0; mt < 6; ++mt){
        int c0 = 16*mt + 4*lg;
        st2(xo + c0,
            pk2(po[mt][0] + xr[4*mt+0], po[mt][1] + xr[4*mt+1]),
            pk2(po[mt][2] + xr[4*mt+2], po[mt][3] + xr[4*mt+3]));
      }
    }
  }
}

// ---------------------------------------------------------------------------
// MLP kernel (r10/r13, proven 72us): 32-pixel wave tiles, 0 barriers.
// LDS 51,200 B -> 3 blocks/CU; bounds(256,3) -> no spill. (r16 verbatim)
// ---------------------------------------------------------------------------
__global__ __launch_bounds__(256, 3) void mlp_kernel(
    const unsigned short* __restrict__ xres,
    const float* __restrict__ g2, const float* __restrict__ b2,
    const float* __restrict__ bf1, const float* __restrict__ bf2,
    const unsigned short* __restrict__ wfr,
    float* __restrict__ out)
{
  __shared__ __align__(16) unsigned short XH[4][6400];
  const int tid = threadIdx.x, lane = tid & 63, w = tid >> 6;
  const int lg = lane >> 4, ln = lane & 15;
  unsigned short* XN2 = &XH[w][0];
  unsigned short* HS  = &XH[w][3200];

  const int tile = blockIdx.x*4 + w;
  const size_t p0 = (size_t)tile * 32;
  const int bimg = (int)(p0 / 50176);
  const size_t pixin = p0 - (size_t)bimg*50176;

#pragma unroll
  for (int s = 0; s < 2; ++s){
    const unsigned* xp = (const unsigned*)(xres + (p0 + 16*s + (size_t)ln)*96 + 24*lg);
    float xv[24];
#pragma unroll
    for (int i = 0; i < 12; ++i){
      unsigned u = xp[i];
      xv[2*i] = bfu(u); xv[2*i+1] = bfu(u >> 16);
    }
    float sm = 0.f, s2 = 0.f;
#pragma unroll
    for (int i = 0; i < 24; ++i){ sm += xv[i]; s2 += xv[i]*xv[i]; }
    sm += __shfl_xor(sm, 16);  sm += __shfl_xor(sm, 32);
    s2 += __shfl_xor(s2, 16);  s2 += __shfl_xor(s2, 32);
    float m = sm * (1.f/96.f);
    float var = s2 * (1.f/96.f) - m*m;
    float rstd = rsqrtf(var + 1e-5f);
    unsigned* w32 = (unsigned*)(XN2 + (16*s + ln)*100 + 24*lg);
#pragma unroll
    for (int i = 0; i < 12; ++i){
      int c = 24*lg + 2*i;
      w32[i] = pk2((xv[2*i]   - m)*rstd*g2[c]   + b2[c],
                   (xv[2*i+1] - m)*rstd*g2[c+1] + b2[c+1]);
    }
  }

  f32x4 oaccA[6], oaccB[6];
#pragma unroll
  for (int mt = 0; mt < 6; ++mt){
    int c0 = 16*mt + 4*lg;
#pragma unroll
    for (int r = 0; r < 4; ++r){ oaccA[mt][r] = bf2[c0+r]; oaccB[mt][r] = bf2[c0+r]; }
  }

  short8 bxA0 = lds8(XN2 + ln*100 + 0  + 8*lg);
  short8 bxA1 = lds8(XN2 + ln*100 + 32 + 8*lg);
  short8 bxA2 = lds8(XN2 + ln*100 + 64 + 8*lg);
  short8 bxB0 = lds8(XN2 + (16+ln)*100 + 0  + 8*lg);
  short8 bxB1 = lds8(XN2 + (16+ln)*100 + 32 + 8*lg);
  short8 bxB2 = lds8(XN2 + (16+ln)*100 + 64 + 8*lg);

#pragma unroll
  for (int p = 0; p < 4; ++p){
#pragma unroll
    for (int mt = 0; mt < 6; ++mt){
      int hg = p*96 + 16*mt + 4*lg;
      f32x4 hA, hB;
#pragma unroll
      for (int r = 0; r < 4; ++r){ hA[r] = bf1[hg+r]; hB[r] = bf1[hg+r]; }
      short8 a0 = gfrag(wfr + 36864 + ((p*6+mt)*3+0)*512 + lane*8);
      short8 a1 = gfrag(wfr + 36864 + ((p*6+mt)*3+1)*512 + lane*8);
      short8 a2 = gfrag(wfr + 36864 + ((p*6+mt)*3+2)*512 + lane*8);
      hA = MFMA(a0, bxA0, hA); hB = MFMA(a0, bxB0, hB);
      hA = MFMA(a1, bxA1, hA); hB = MFMA(a1, bxB1, hB);
      hA = MFMA(a2, bxA2, hA); hB = MFMA(a2, bxB2, hB);
      st2(HS + ln*100 + 16*mt + 4*lg,
          pk2(gelu_f(hA[0]), gelu_f(hA[1])), pk2(gelu_f(hA[2]), gelu_f(hA[3])));
      st2(HS + (16+ln)*100 + 16*mt + 4*lg,
          pk2(gelu_f(hB[0]), gelu_f(hB[1])), pk2(gelu_f(hB[2]), gelu_f(hB[3])));
    }
#pragma unroll
    for (int kb = 0; kb < 3; ++kb){
      short8 bhA = lds8(HS + ln*100      + 32*kb + 8*lg);
      short8 bhB = lds8(HS + (16+ln)*100 + 32*kb + 8*lg);
#pragma unroll
      for (int mt = 0; mt < 6; ++mt){
        short8 af = gfrag(wfr + 73728 + (mt*12 + p*3 + kb)*512 + lane*8);
        oaccA[mt] = MFMA(af, bhA, oaccA[mt]);
        oaccB[mt] = MFMA(af, bhB, oaccB[mt]);
      }
    }
  }

  {
    const unsigned short* xrA = xres + (p0 + (size_t)ln)*96;
    const unsigned short* xrB = xrA + 16*96;
    float* obA = out + (size_t)bimg*96*50176 + pixin + ln;
    float* obB = obA + 16;
#pragma unroll
    for (int mt = 0; mt < 6; ++mt){
      int c0 = 16*mt + 4*lg;
      U2 rA = *(const U2*)(xrA + c0);
      U2 rB = *(const U2*)(xrB + c0);
      obA[(size_t)(c0+0)*50176] = oaccA[mt][0] + bfu(rA.x);
      obA[(size_t)(c0+1)*50176] = oaccA[mt][1] + bfu(rA.x >> 16);
      obA[(size_t)(c0+2)*50176] = oaccA[mt][2] + bfu(rA.y);
      obA[(size_t)(c0+3)*50176] = oaccA[mt][3] + bfu(rA.y >> 16);
      obB[(size_t)(c0+0)*50176] = oaccB[mt][0] + bfu(rB.x);
      obB[(size_t)(c0+1)*50176] = oaccB[mt][1] + bfu(rB.x >> 16);
      obB[(size_t)(c0+2)*50176] = oaccB[mt][2] + bfu(rB.y);
      obB[(size_t)(c0+3)*50176] = oaccB[mt][3] + bfu(rB.y >> 16);
    }
  }
}

extern "C" void kernel_launch(void* const* d_in, const int* in_sizes, int n_in,
                              void* d_out, int out_size, void* d_ws, size_t ws_size,
                              hipStream_t stream) {
  const float* x    = (const float*)d_in[0];
  const float* emap = (const float*)d_in[1];
  const float* beta = (const float*)d_in[2];
  const float* wq   = (const float*)d_in[3];
  const float* bq   = (const float*)d_in[4];
  const float* wk   = (const float*)d_in[5];
  const float* bk   = (const float*)d_in[6];
  const float* wv   = (const float*)d_in[7];
  const float* bv   = (const float*)d_in[8];
  const float* wo   = (const float*)d_in[9];
  const float* bo   = (const float*)d_in[10];
  const float* g1   = (const float*)d_in[11];
  const float* b1   = (const float*)d_in[12];
  const float* g2   = (const float*)d_in[13];
  const float* b2   = (const float*)d_in[14];
  const float* w1   = (const float*)d_in[15];
  const float* bf1  = (const float*)d_in[16];
  const float* w2   = (const float*)d_in[17];
  const float* bf2  = (const float*)d_in[18];

  float* out = (float*)d_out;
  unsigned short* wfr  = (unsigned short*)d_ws;                       // 221 KB fragments
  unsigned short* xres = (unsigned short*)((char*)d_ws + 262144);     // 77 MB bf16 [pix][96]

  prep_kernel<<<dim3(432), dim3(256), 0, stream>>>(wq, wk, wv, wo, w1, w2, wfr);
  attn_kernel<<<dim3(8192), dim3(256), 0, stream>>>(
      x, emap, beta, bq, bk, bv, bo, g1, b1, wfr, xres);
  mlp_kernel<<<dim3(3136), dim3(256), 0, stream>>>(
      xres, g2, b2, bf1, bf2, wfr, out);
}

// Round 18
// 349.684 us; speedup vs baseline: 1.0910x; 1.0910x over previous
//
#include <hip/hip_runtime.h>
#include <hip/hip_bf16.h>
#include <math.h>

typedef __attribute__((ext_vector_type(8))) short short8;
typedef __attribute__((ext_vector_type(4))) float f32x4;
typedef __attribute__((ext_vector_type(4))) unsigned int uint4v;

struct __align__(8) U2 { unsigned int x, y; };

#define DEVI static __device__ __forceinline__

DEVI unsigned pk1(float f){ unsigned u = __float_as_uint(f); return (u + 0x7fffu + ((u>>16)&1u)) >> 16; }
DEVI unsigned pk2(float a, float b){
  __hip_bfloat162 h = __float22bfloat162_rn(float2{a, b});   // v_cvt_pk_bf16_f32 (RNE)
  union { __hip_bfloat162 h; unsigned u; } c; c.h = h; return c.u;
}
DEVI float bfu(unsigned hs){ return __uint_as_float((hs & 0xffffu) << 16); }

DEVI short8 lds8(const unsigned short* p){
  union { short8 v; U2 u[2]; } f;
  f.u[0] = *(const U2*)p;
  f.u[1] = *(const U2*)(p + 4);
  return f.v;
}
DEVI short8 mk8(unsigned a, unsigned b, unsigned c, unsigned d){
  union { short8 v; unsigned u[4]; } f; f.u[0]=a; f.u[1]=b; f.u[2]=c; f.u[3]=d; return f.v;
}
DEVI short8 zero8(){ return mk8(0,0,0,0); }
DEVI short8 gfrag(const unsigned short* p){ union { short8 v; uint4v u; } f; f.u = *(const uint4v*)p; return f.v; }
DEVI f32x4 MFMA(short8 a, short8 b, f32x4 c){ return __builtin_amdgcn_mfma_f32_16x16x32_bf16(a, b, c, 0, 0, 0); }
DEVI void st2(unsigned short* p, unsigned lo, unsigned hi){ U2 t; t.x=lo; t.y=hi; *(U2*)p = t; }

DEVI float fastrcp(float x){ float r; asm("v_rcp_f32 %0, %1" : "=v"(r) : "v"(x)); return r; }
// tanh-form GELU: v * sigmoid(1.5957691*(v + 0.044715 v^3)); max err ~3e-4
DEVI float gelu_f(float v){
  float z2 = fmaf(v*v*v, -0.07135481627f, -1.5957691216f*v);
  return v * fastrcp(1.f + __expf(z2));
}

// ---------------------------------------------------------------------------
// prep: swizzle weights into bf16 MFMA fragment arrays in ws.
// Fragment map (same map for ALL consumers, so K-permutation cancels):
// m/n = 16*mt + (lane&15), k = 32*kb + 8*(lane>>4) + j.
// wq fragments pre-scaled by 1/sqrt(24).
// Offsets (ushort): AQT=0, AKT=9216, BV=18432, AOT=27648, A1T=36864, A2T=73728
// ---------------------------------------------------------------------------
__global__ __launch_bounds__(256) void prep_kernel(
    const float* __restrict__ wq, const float* __restrict__ wk,
    const float* __restrict__ wv, const float* __restrict__ wo,
    const float* __restrict__ w1, const float* __restrict__ w2,
    unsigned short* __restrict__ wfr)
{
  int i = blockIdx.x * 256 + threadIdx.x;
  if (i >= 110592) return;
  int j = i & 7, lane = (i >> 3) & 63, fr = i >> 9;
  int ln = lane & 15, lg = lane >> 4;
  float v;
  if (fr < 18)      { int s = fr;       int mt = s/3,  kb = s%3;  v = wq[(32*kb + 8*lg + j)*96  + 16*mt + ln] * 0.20412414523193150818f; }
  else if (fr < 36) { int s = fr - 18;  int mt = s/3,  kb = s%3;  v = wk[(32*kb + 8*lg + j)*96  + 16*mt + ln]; }
  else if (fr < 54) { int s = fr - 36;  int mt = s/3,  kb = s%3;  v = wv[(32*kb + 8*lg + j)*96  + 16*mt + ln]; }
  else if (fr < 72) { int s = fr - 54;  int mt = s/3,  kb = s%3;  v = wo[(32*kb + 8*lg + j)*96  + 16*mt + ln]; }
  else if (fr < 144){ int s = fr - 72;  int mt = s/3,  kb = s%3;  v = w1[(32*kb + 8*lg + j)*384 + 16*mt + ln]; }
  else              { int s = fr - 144; int mt = s/12, kb = s%12; v = w2[(32*kb + 8*lg + j)*96  + 16*mt + ln]; }
  wfr[i] = (unsigned short)pk1(v);
}

// ---------------------------------------------------------------------------
// Attention kernel: one 7x7 window per block, 4 waves, 2 barriers.
// r7 layout (proven): LDS 52,544 B -> 3 blocks/CU; XN | QS | KS | VT.
// ph3 processes heads in PAIRS (two independent score->softmax->shfl->PV
// chains interleaved) for 2x per-wave ILP. Best-measured config (r11).
// ---------------------------------------------------------------------------
__global__ __launch_bounds__(256, 3) void attn_kernel(
    const float* __restrict__ x, const float* __restrict__ emap,
    const float* __restrict__ beta_p,
    const float* __restrict__ bq, const float* __restrict__ bk,
    const float* __restrict__ bv, const float* __restrict__ bo,
    const float* __restrict__ g1, const float* __restrict__ b1,
    const unsigned short* __restrict__ wfr,
    unsigned short* __restrict__ xres)
{
  __shared__ __align__(16) char smem[52544];
  unsigned short* XN = (unsigned short*)(smem);            // [64][100] xn -> o_s
  unsigned short* QS = (unsigned short*)(smem + 12800);    // [64][100] q (wave-local)
  unsigned short* KS = (unsigned short*)(smem + 25600);    // [64][100] k
  unsigned short* VT = (unsigned short*)(smem + 38400);    // [104][68] v^T

  const int tid = threadIdx.x;
  const int lane = tid & 63;
  const int w = tid >> 6, lg = lane >> 4, ln = lane & 15;

  int bid = blockIdx.x;
  int bw  = ((bid & 7) << 10) | (bid >> 3);   // XCD swizzle: one image per XCD
  const int b  = bw >> 10;
  const int rr = bw & 1023;
  const int h0w = (rr >> 5) * 7;
  const int w0w = (rr & 31) * 7;

  const int t = 16*w + ln;

  // ---- ph1: x -> regs (fragment-aligned channels), LN1 -> XN own rows ----
  float xv[24];        // lane (lg,ln): channels 16*mt + 4*lg + r, token t
  float ewv = 0.f;
  {
    if (t < 49){
      size_t pixloc = (size_t)(h0w + t/7)*224 + w0w + t%7;
      const float* xp = x + (size_t)(b*96 + 4*lg)*50176 + pixloc;
#pragma unroll
      for (int mt = 0; mt < 6; ++mt)
#pragma unroll
        for (int r = 0; r < 4; ++r) xv[mt*4+r] = xp[(size_t)(16*mt + r)*50176];
      ewv = emap[(size_t)b*50176 + pixloc];
    } else {
#pragma unroll
      for (int i = 0; i < 24; ++i) xv[i] = 0.f;
    }
    float s = 0.f, s2 = 0.f;
#pragma unroll
    for (int i = 0; i < 24; ++i){ s += xv[i]; s2 += xv[i]*xv[i]; }
    s  += __shfl_xor(s, 16);  s  += __shfl_xor(s, 32);
    s2 += __shfl_xor(s2, 16); s2 += __shfl_xor(s2, 32);
    float m = s * (1.f/96.f);
    float var = s2 * (1.f/96.f) - m*m;
    float rstd = rsqrtf(var + 1e-5f);
    unsigned short* row = XN + t*100;
    if (t < 49){
#pragma unroll
      for (int mt = 0; mt < 6; ++mt){
        int c0 = 16*mt + 4*lg;
        st2(row + c0,
            pk2((xv[4*mt+0]-m)*rstd*g1[c0+0]+b1[c0+0], (xv[4*mt+1]-m)*rstd*g1[c0+1]+b1[c0+1]),
            pk2((xv[4*mt+2]-m)*rstd*g1[c0+2]+b1[c0+2], (xv[4*mt+3]-m)*rstd*g1[c0+3]+b1[c0+3]));
      }
    } else {
#pragma unroll
      for (int mt = 0; mt < 6; ++mt) st2(row + 16*mt + 4*lg, 0u, 0u);
    }
  }
  __syncthreads();   // barrier 1: xn published

  // ---- ph2: QKV -> QS (wave-local), KS, VT ----
  {
    short8 bx0 = lds8(XN + t*100 + 0  + 8*lg);
    short8 bx1 = lds8(XN + t*100 + 32 + 8*lg);
    short8 bx2 = lds8(XN + t*100 + 64 + 8*lg);
#pragma unroll
    for (int mt = 0; mt < 6; ++mt){
      int d0 = 16*mt + 4*lg;
      f32x4 aq, ak;
#pragma unroll
      for (int r = 0; r < 4; ++r){ aq[r] = bq[d0+r]*0.20412414523193150818f; ak[r] = bk[d0+r]; }
      aq = MFMA(gfrag(wfr +        (mt*3+0)*512 + lane*8), bx0, aq);
      aq = MFMA(gfrag(wfr +        (mt*3+1)*512 + lane*8), bx1, aq);
      aq = MFMA(gfrag(wfr +        (mt*3+2)*512 + lane*8), bx2, aq);
      ak = MFMA(gfrag(wfr + 9216 + (mt*3+0)*512 + lane*8), bx0, ak);
      ak = MFMA(gfrag(wfr + 9216 + (mt*3+1)*512 + lane*8), bx1, ak);
      ak = MFMA(gfrag(wfr + 9216 + (mt*3+2)*512 + lane*8), bx2, ak);
      st2(QS + t*100 + d0, pk2(aq[0],aq[1]), pk2(aq[2],aq[3]));
      st2(KS + t*100 + d0, pk2(ak[0],ak[1]), pk2(ak[2],ak[3]));
    }
#pragma unroll
    for (int f = 0; f < 6; ++f){
      int fl = f*4 + w;
      int mt = fl / 6, nt = fl % 6;
      float bvv = bv[16*nt + ln];
      f32x4 av; av[0]=bvv; av[1]=bvv; av[2]=bvv; av[3]=bvv;
#pragma unroll
      for (int kb = 0; kb < 3; ++kb)
        av = MFMA(lds8(XN + (16*mt+ln)*100 + 32*kb + 8*lg),
                  gfrag(wfr + 18432 + (nt*3+kb)*512 + lane*8), av);
      st2(VT + (16*nt+ln)*68 + 16*mt + 4*lg, pk2(av[0],av[1]), pk2(av[2],av[3]));
    }
  }
  __syncthreads();   // barrier 2: q/k/vT published. No more barriers.

  // ---- ph3: attention, heads processed in PAIRS for 2x ILP ----
  const float beta = beta_p[0];
  const float gq   = __expf(-beta * ewv);
  const float gfac = gq / (gq + 1e-9f);
  const int  psrcA = ((lg & 1) << 5) + ln;
  const int  psrcB = psrcA + 16;
  const bool phi   = (lg >= 2);

  f32x4 mz;  mz[0]=0.f; mz[1]=0.f; mz[2]=0.f; mz[3]=0.f;
  f32x4 m3;  // pad-key mask for key tile mt=3 (keys 48+4lg+r; key 48 valid)
#pragma unroll
  for (int r = 0; r < 4; ++r) m3[r] = (4*lg + r >= 1) ? -50.f : 0.f;

#pragma unroll
  for (int hp = 0; hp < 2; ++hp){
    const int h0 = 2*hp, h1 = 2*hp + 1;

    // scores for both heads (independent chains)
    short8 bqf0 = (lg < 3) ? lds8(QS + t*100 + 24*h0 + 8*lg) : zero8();
    short8 bqf1 = (lg < 3) ? lds8(QS + t*100 + 24*h1 + 8*lg) : zero8();
    f32x4 sv0[4], sv1[4];
#pragma unroll
    for (int mt = 0; mt < 4; ++mt){
      short8 af0 = (lg < 3) ? lds8(KS + (16*mt+ln)*100 + 24*h0 + 8*lg) : zero8();
      short8 af1 = (lg < 3) ? lds8(KS + (16*mt+ln)*100 + 24*h1 + 8*lg) : zero8();
      f32x4 ci = (mt == 3) ? m3 : mz;
      sv0[mt] = MFMA(af0, bqf0, ci);
      sv1[mt] = MFMA(af1, bqf1, ci);
    }

    // softmax (no max-sub; scores provably small), both heads interleaved
    float vv0[16], vv1[16];
    float ss0 = 0.f, ss1 = 0.f;
#pragma unroll
    for (int i = 0; i < 16; ++i){
      float e0 = __expf(sv0[i>>2][i&3]); vv0[i] = e0; ss0 += e0;
      float e1 = __expf(sv1[i>>2][i&3]); vv1[i] = e1; ss1 += e1;
    }
    ss0 += __shfl_xor(ss0, 16);  ss1 += __shfl_xor(ss1, 16);
    ss0 += __shfl_xor(ss0, 32);  ss1 += __shfl_xor(ss1, 32);
    float inv0 = gfac * fastrcp(ss0);
    float inv1 = gfac * fastrcp(ss1);

    unsigned pu0[4][2], pu1[4][2];
#pragma unroll
    for (int mt = 0; mt < 4; ++mt){
      pu0[mt][0] = pk2(vv0[4*mt+0], vv0[4*mt+1]);
      pu0[mt][1] = pk2(vv0[4*mt+2], vv0[4*mt+3]);
      pu1[mt][0] = pk2(vv1[4*mt+0], vv1[4*mt+1]);
      pu1[mt][1] = pk2(vv1[4*mt+2], vv1[4*mt+3]);
    }

    // P-fragment gather via shfl, both heads interleaved
    unsigned a00=__shfl(pu0[0][0],psrcA), a01=__shfl(pu0[0][1],psrcA);
    unsigned e00=__shfl(pu1[0][0],psrcA), e01=__shfl(pu1[0][1],psrcA);
    unsigned a10=__shfl(pu0[1][0],psrcA), a11=__shfl(pu0[1][1],psrcA);
    unsigned e10=__shfl(pu1[1][0],psrcA), e11=__shfl(pu1[1][1],psrcA);
    unsigned b00=__shfl(pu0[0][0],psrcB), b01=__shfl(pu0[0][1],psrcB);
    unsigned f00=__shfl(pu1[0][0],psrcB), f01=__shfl(pu1[0][1],psrcB);
    unsigned b10=__shfl(pu0[1][0],psrcB), b11=__shfl(pu0[1][1],psrcB);
    unsigned f10=__shfl(pu1[1][0],psrcB), f11=__shfl(pu1[1][1],psrcB);
    short8 pf00 = mk8(phi?a10:a00, phi?a11:a01, phi?b10:b00, phi?b11:b01);
    short8 pf10 = mk8(phi?e10:e00, phi?e11:e01, phi?f10:f00, phi?f11:f01);
    unsigned c00=__shfl(pu0[2][0],psrcA), c01=__shfl(pu0[2][1],psrcA);
    unsigned g00=__shfl(pu1[2][0],psrcA), g01=__shfl(pu1[2][1],psrcA);
    unsigned c10=__shfl(pu0[3][0],psrcA), c11=__shfl(pu0[3][1],psrcA);
    unsigned g10=__shfl(pu1[3][0],psrcA), g11=__shfl(pu1[3][1],psrcA);
    unsigned d00=__shfl(pu0[2][0],psrcB), d01=__shfl(pu0[2][1],psrcB);
    unsigned k00=__shfl(pu1[2][0],psrcB), k01=__shfl(pu1[2][1],psrcB);
    unsigned d10=__shfl(pu0[3][0],psrcB), d11=__shfl(pu0[3][1],psrcB);
    unsigned k10=__shfl(pu1[3][0],psrcB), k11=__shfl(pu1[3][1],psrcB);
    short8 pf01 = mk8(phi?c10:c00, phi?c11:c01, phi?d10:d00, phi?d11:d01);
    short8 pf11 = mk8(phi?g10:g00, phi?g11:g01, phi?k10:k00, phi?k11:k01);

    // PV for both heads
#pragma unroll
    for (int mt = 0; mt < 2; ++mt){
      f32x4 pv0; pv0[0]=0.f; pv0[1]=0.f; pv0[2]=0.f; pv0[3]=0.f;
      f32x4 pv1; pv1[0]=0.f; pv1[1]=0.f; pv1[2]=0.f; pv1[3]=0.f;
      pv0 = MFMA(lds8(VT + (24*h0+16*mt+ln)*68 + 0  + 8*lg), pf00, pv0);
      pv1 = MFMA(lds8(VT + (24*h1+16*mt+ln)*68 + 0  + 8*lg), pf10, pv1);
      pv0 = MFMA(lds8(VT + (24*h0+16*mt+ln)*68 + 32 + 8*lg), pf01, pv0);
      pv1 = MFMA(lds8(VT + (24*h1+16*mt+ln)*68 + 32 + 8*lg), pf11, pv1);
      if (!(mt == 1 && lg >= 2)){
        st2(XN + t*100 + 24*h0 + 16*mt + 4*lg,
            pk2(pv0[0]*inv0, pv0[1]*inv0), pk2(pv0[2]*inv0, pv0[3]*inv0));
        st2(XN + t*100 + 24*h1 + 16*mt + 4*lg,
            pk2(pv1[0]*inv1, pv1[1]*inv1), pk2(pv1[2]*inv1, pv1[3]*inv1));
      }
    }
  }

  // ---- ph4: proj + residual (from regs) -> xres bf16 [pix][96] ----
  {
    f32x4 po[6];
#pragma unroll
    for (int mt = 0; mt < 6; ++mt){
      int c0 = 16*mt + 4*lg;
#pragma unroll
      for (int r = 0; r < 4; ++r) po[mt][r] = bo[c0+r];
    }
#pragma unroll
    for (int kb = 0; kb < 3; ++kb){
      short8 bf_ = lds8(XN + t*100 + 32*kb + 8*lg);   // own row (o_s), all heads done
#pragma unroll
      for (int mt = 0; mt < 6; ++mt)
        po[mt] = MFMA(gfrag(wfr + 27648 + (mt*3+kb)*512 + lane*8), bf_, po[mt]);
    }
    if (t < 49){
      size_t pixloc = (size_t)(h0w + t/7)*224 + w0w + t%7;
      unsigned short* xo = xres + ((size_t)b*50176 + pixloc)*96;
#pragma unroll
      for (int mt = 0; mt < 6; ++mt){
        int c0 = 16*mt + 4*lg;
        st2(xo + c0,
            pk2(po[mt][0] + xv[4*mt+0], po[mt][1] + xv[4*mt+1]),
            pk2(po[mt][2] + xv[4*mt+2], po[mt][3] + xv[4*mt+3]));
      }
    }
  }
}

// ---------------------------------------------------------------------------
// MLP kernel: wave-independent 32-pixel tiles (two 16-px sets A/B), 0 barriers.
// Each weight A-fragment load feeds TWO MFMAs -> L2 frag traffic halved.
// LDS 51,200 B -> 3 blocks/CU; launch_bounds(256,3) -> no spill.
// grid = 3136 x 256 (12544 wave-tiles of 32 pixels).
// ---------------------------------------------------------------------------
__global__ __launch_bounds__(256, 3) void mlp_kernel(
    const unsigned short* __restrict__ xres,
    const float* __restrict__ g2, const float* __restrict__ b2,
    const float* __restrict__ bf1, const float* __restrict__ bf2,
    const unsigned short* __restrict__ wfr,
    float* __restrict__ out)
{
  __shared__ __align__(16) unsigned short XH[4][6400];  // per wave: xn2[32][100] + hs[32][100]
  const int tid = threadIdx.x, lane = tid & 63, w = tid >> 6;
  const int lg = lane >> 4, ln = lane & 15;
  unsigned short* XN2 = &XH[w][0];
  unsigned short* HS  = &XH[w][3200];

  const int tile = blockIdx.x*4 + w;
  const size_t p0 = (size_t)tile * 32;
  const int bimg = (int)(p0 / 50176);
  const size_t pixin = p0 - (size_t)bimg*50176;

  // LN2 for both pixel sets (s=0: pixel p0+ln, s=1: pixel p0+16+ln)
#pragma unroll
  for (int s = 0; s < 2; ++s){
    const unsigned* xp = (const unsigned*)(xres + (p0 + 16*s + (size_t)ln)*96 + 24*lg);
    float xv[24];
#pragma unroll
    for (int i = 0; i < 12; ++i){
      unsigned u = xp[i];
      xv[2*i] = bfu(u); xv[2*i+1] = bfu(u >> 16);
    }
    float sm = 0.f, s2 = 0.f;
#pragma unroll
    for (int i = 0; i < 24; ++i){ sm += xv[i]; s2 += xv[i]*xv[i]; }
    sm += __shfl_xor(sm, 16);  sm += __shfl_xor(sm, 32);
    s2 += __shfl_xor(s2, 16);  s2 += __shfl_xor(s2, 32);
    float m = sm * (1.f/96.f);
    float var = s2 * (1.f/96.f) - m*m;
    float rstd = rsqrtf(var + 1e-5f);
    unsigned* w32 = (unsigned*)(XN2 + (16*s + ln)*100 + 24*lg);
#pragma unroll
    for (int i = 0; i < 12; ++i){
      int c = 24*lg + 2*i;
      w32[i] = pk2((xv[2*i]   - m)*rstd*g2[c]   + b2[c],
                   (xv[2*i+1] - m)*rstd*g2[c+1] + b2[c+1]);
    }
  }

  f32x4 oaccA[6], oaccB[6];
#pragma unroll
  for (int mt = 0; mt < 6; ++mt){
    int c0 = 16*mt + 4*lg;
#pragma unroll
    for (int r = 0; r < 4; ++r){ oaccA[mt][r] = bf2[c0+r]; oaccB[mt][r] = bf2[c0+r]; }
  }

  short8 bxA0 = lds8(XN2 + ln*100 + 0  + 8*lg);
  short8 bxA1 = lds8(XN2 + ln*100 + 32 + 8*lg);
  short8 bxA2 = lds8(XN2 + ln*100 + 64 + 8*lg);
  short8 bxB0 = lds8(XN2 + (16+ln)*100 + 0  + 8*lg);
  short8 bxB1 = lds8(XN2 + (16+ln)*100 + 32 + 8*lg);
  short8 bxB2 = lds8(XN2 + (16+ln)*100 + 64 + 8*lg);

#pragma unroll
  for (int p = 0; p < 4; ++p){
    // FC1 tile p: hidden cols [p*96, p*96+96); one A-frag load -> 2 MFMAs
#pragma unroll
    for (int mt = 0; mt < 6; ++mt){
      int hg = p*96 + 16*mt + 4*lg;
      f32x4 hA, hB;
#pragma unroll
      for (int r = 0; r < 4; ++r){ hA[r] = bf1[hg+r]; hB[r] = bf1[hg+r]; }
      short8 a0 = gfrag(wfr + 36864 + ((p*6+mt)*3+0)*512 + lane*8);
      short8 a1 = gfrag(wfr + 36864 + ((p*6+mt)*3+1)*512 + lane*8);
      short8 a2 = gfrag(wfr + 36864 + ((p*6+mt)*3+2)*512 + lane*8);
      hA = MFMA(a0, bxA0, hA); hB = MFMA(a0, bxB0, hB);
      hA = MFMA(a1, bxA1, hA); hB = MFMA(a1, bxB1, hB);
      hA = MFMA(a2, bxA2, hA); hB = MFMA(a2, bxB2, hB);
      st2(HS + ln*100 + 16*mt + 4*lg,
          pk2(gelu_f(hA[0]), gelu_f(hA[1])), pk2(gelu_f(hA[2]), gelu_f(hA[3])));
      st2(HS + (16+ln)*100 + 16*mt + 4*lg,
          pk2(gelu_f(hB[0]), gelu_f(hB[1])), pk2(gelu_f(hB[2]), gelu_f(hB[3])));
    }
    // FC2 partial over this hidden tile
#pragma unroll
    for (int kb = 0; kb < 3; ++kb){
      short8 bhA = lds8(HS + ln*100      + 32*kb + 8*lg);
      short8 bhB = lds8(HS + (16+ln)*100 + 32*kb + 8*lg);
#pragma unroll
      for (int mt = 0; mt < 6; ++mt){
        short8 af = gfrag(wfr + 73728 + (mt*12 + p*3 + kb)*512 + lane*8);
        oaccA[mt] = MFMA(af, bhA, oaccA[mt]);
        oaccB[mt] = MFMA(af, bhB, oaccB[mt]);
      }
    }
  }

  // epilogue: residual re-read (L3-hot) + store to (B,C,H,W), both sets
  {
    const unsigned short* xrA = xres + (p0 + (size_t)ln)*96;
    const unsigned short* xrB = xrA + 16*96;
    float* obA = out + (size_t)bimg*96*50176 + pixin + ln;
    float* obB = obA + 16;
#pragma unroll
    for (int mt = 0; mt < 6; ++mt){
      int c0 = 16*mt + 4*lg;
      U2 rA = *(const U2*)(xrA + c0);
      U2 rB = *(const U2*)(xrB + c0);
      obA[(size_t)(c0+0)*50176] = oaccA[mt][0] + bfu(rA.x);
      obA[(size_t)(c0+1)*50176] = oaccA[mt][1] + bfu(rA.x >> 16);
      obA[(size_t)(c0+2)*50176] = oaccA[mt][2] + bfu(rA.y);
      obA[(size_t)(c0+3)*50176] = oaccA[mt][3] + bfu(rA.y >> 16);
      obB[(size_t)(c0+0)*50176] = oaccB[mt][0] + bfu(rB.x);
      obB[(size_t)(c0+1)*50176] = oaccB[mt][1] + bfu(rB.x >> 16);
      obB[(size_t)(c0+2)*50176] = oaccB[mt][2] + bfu(rB.y);
      obB[(size_t)(c0+3)*50176] = oaccB[mt][3] + bfu(rB.y >> 16);
    }
  }
}

extern "C" void kernel_launch(void* const* d_in, const int* in_sizes, int n_in,
                              void* d_out, int out_size, void* d_ws, size_t ws_size,
                              hipStream_t stream) {
  const float* x    = (const float*)d_in[0];
  const float* emap = (const float*)d_in[1];
  const float* beta = (const float*)d_in[2];
  const float* wq   = (const float*)d_in[3];
  const float* bq   = (const float*)d_in[4];
  const float* wk   = (const float*)d_in[5];
  const float* bk   = (const float*)d_in[6];
  const float* wv   = (const float*)d_in[7];
  const float* bv   = (const float*)d_in[8];
  const float* wo   = (const float*)d_in[9];
  const float* bo   = (const float*)d_in[10];
  const float* g1   = (const float*)d_in[11];
  const float* b1   = (const float*)d_in[12];
  const float* g2   = (const float*)d_in[13];
  const float* b2   = (const float*)d_in[14];
  const float* w1   = (const float*)d_in[15];
  const float* bf1  = (const float*)d_in[16];
  const float* w2   = (const float*)d_in[17];
  const float* bf2  = (const float*)d_in[18];

  float* out = (float*)d_out;
  unsigned short* wfr  = (unsigned short*)d_ws;                       // 221 KB fragments
  unsigned short* xres = (unsigned short*)((char*)d_ws + 262144);     // 77 MB bf16 [pix][96]

  prep_kernel<<<dim3(432), dim3(256), 0, stream>>>(wq, wk, wv, wo, w1, w2, wfr);
  attn_kernel<<<dim3(8192), dim3(256), 0, stream>>>(
      x, emap, beta, bq, bk, bv, bo, g1, b1, wfr, xres);
  mlp_kernel<<<dim3(3136), dim3(256), 0, stream>>>(
      xres, g2, b2, bf1, bf2, wfr, out);
}